// Round 7
// baseline (98.405 us; speedup 1.0000x reference)
//
#include <hip/hip_runtime.h>

// Problem constants (match reference)
#define HH    128
#define WW    128
#define CDIM  4
#define DK    3
#define FDIM  4
#define DEPTH 16
#define DOUT  14
#define NB    4
#define HW    (HH * WW)          // 16384
#define TROWS 4                  // output rows per block
#define HROWS (TROWS + 2)        // halo rows of Q per block
#define NTILE (HH / TROWS)       // 32 h-tiles
#define IB    4                  // i-values per block
#define NIG   4                  // i-groups: {0-3,4-7,8-11,12-13(partial)}
#define NPL   (IB + DK - 1)      // 6 x-planes per c

typedef float nfloat4 __attribute__((ext_vector_type(4)));  // native vec for nt-store

// ---------------------------------------------------------------------------
// Kernel A: bsum[f,h,w] = sum_{c,dd} bias[f,0,c,dd,h,w]   (float4-vectorized)
// ---------------------------------------------------------------------------
__global__ __launch_bounds__(256) void bsum_kernel(const float4* __restrict__ bias,
                                                   float4* __restrict__ bsum) {
    int idx = blockIdx.x * 256 + threadIdx.x;     // over f*H*W/4 = 16384
    int f   = idx >> 12;
    int hw4 = idx & 4095;
    const float4* bp = bias + f * (CDIM * DK * (HW / 4)) + hw4;
    float4 s = make_float4(0.f, 0.f, 0.f, 0.f);
#pragma unroll
    for (int c = 0; c < CDIM; ++c)
#pragma unroll
        for (int dd = 0; dd < DK; ++dd) {
            float4 v = bp[(c * DK + dd) * (HW / 4)];
            s.x += v.x; s.y += v.y; s.z += v.z; s.w += v.w;
        }
    bsum[idx] = s;
}

// ---------------------------------------------------------------------------
// Kernel B: fused Q + 3x3 box-sum + leaky ReLU, 4 depth-outputs per block.
// 384 threads = 6 waves; wave r handles halo row r. Within a wave, lanes
// 0-31 accumulate c=0,1 and lanes 32-63 accumulate c=2,3 for the same
// (row, q); partial sums combined via __shfl_xor(...,32). This halves the
// per-wave serial load/FMA chain at constant total loads -> 3 waves/SIMD
// of latency hiding instead of 1.5.
// ---------------------------------------------------------------------------
__global__ __launch_bounds__(384, 3) void linerconv_main(const float* __restrict__ x,
                                                         const float* __restrict__ wgt,
                                                         const float* __restrict__ bsum,
                                                         float* __restrict__ out) {
    const int blk  = blockIdx.x;
    const int tile = blk & (NTILE - 1);
    const int ig   = (blk >> 5) & (NIG - 1);
    const int b    = blk >> 7;
    const int i0   = ig * IB;                 // 0,4,8,12 (last group: 2 i only)
    const int h0   = tile * TROWS;

    __shared__ float lds[IB][FDIM][HROWS][WW]; // 4*4*6*128*4B = 48 KB

    const int tid   = threadIdx.x;
    const int row   = tid >> 6;               // wave id = halo row 0..5
    const int lane  = tid & 63;
    const int chalf = lane >> 5;              // 0: c=0,1   1: c=2,3
    const int q     = lane & 31;
    const int g     = h0 - 1 + row;

    // ---- Phase 1 ----
    if (g >= 0 && g < HH) {
        const int base_hw = g * WW + q * 4;
        const float* xb = x + (b * CDIM * DEPTH + i0) * HW + base_hw;
        const float* wb = wgt + base_hw;
        float4 acc[IB][FDIM];
        if (chalf == 0) {
#pragma unroll
            for (int f = 0; f < FDIM; ++f) {
                float4 bv = *(const float4*)(bsum + f * HW + base_hw);
#pragma unroll
                for (int i2 = 0; i2 < IB; ++i2) acc[i2][f] = bv;
            }
        } else {
            float4 z = make_float4(0.f, 0.f, 0.f, 0.f);
#pragma unroll
            for (int i2 = 0; i2 < IB; ++i2)
#pragma unroll
                for (int f = 0; f < FDIM; ++f) acc[i2][f] = z;
        }
#pragma unroll
        for (int c2 = 0; c2 < 2; ++c2) {
            const int c = chalf * 2 + c2;
            float4 xp[NPL];                   // planes i0 .. i0+5 (guarded)
#pragma unroll
            for (int j = 0; j < NPL; ++j)
                xp[j] = (i0 + j < DEPTH)
                      ? *(const float4*)(xb + c * (DEPTH * HW) + j * HW)
                      : make_float4(0.f, 0.f, 0.f, 0.f);
#pragma unroll
            for (int dd = 0; dd < DK; ++dd) {
#pragma unroll
                for (int f = 0; f < FDIM; ++f) {
                    float4 wv = *(const float4*)(wb + ((f * CDIM + c) * DK + dd) * HW);
#pragma unroll
                    for (int i2 = 0; i2 < IB; ++i2) {
                        acc[i2][f].x += xp[i2 + dd].x * wv.x;
                        acc[i2][f].y += xp[i2 + dd].y * wv.y;
                        acc[i2][f].z += xp[i2 + dd].z * wv.z;
                        acc[i2][f].w += xp[i2 + dd].w * wv.w;
                    }
                }
            }
        }
        // combine the two c-halves across the 32-lane boundary
#pragma unroll
        for (int i2 = 0; i2 < IB; ++i2)
#pragma unroll
            for (int f = 0; f < FDIM; ++f) {
                acc[i2][f].x += __shfl_xor(acc[i2][f].x, 32);
                acc[i2][f].y += __shfl_xor(acc[i2][f].y, 32);
                acc[i2][f].z += __shfl_xor(acc[i2][f].z, 32);
                acc[i2][f].w += __shfl_xor(acc[i2][f].w, 32);
            }
        // each half writes 2 i2-planes
        const int i2b = chalf * 2;
#pragma unroll
        for (int k = 0; k < 2; ++k)
#pragma unroll
            for (int f = 0; f < FDIM; ++f)
                *(float4*)&lds[i2b + k][f][row][q * 4] = acc[i2b + k][f];
    } else {
        float4 z = make_float4(0.f, 0.f, 0.f, 0.f);
        const int i2b = chalf * 2;
#pragma unroll
        for (int k = 0; k < 2; ++k)
#pragma unroll
            for (int f = 0; f < FDIM; ++f)
                *(float4*)&lds[i2b + k][f][row][q * 4] = z;
    }
    __syncthreads();

    // ---- Phase 2: vectorized column box sums + leaky, float4 nt-stores ----
    // quad-columns: (i2, f, q) = 4*4*32 = 512 over 384 threads.
    for (int u = tid; u < IB * FDIM * 32; u += 384) {
        const int uq = u & 31;
        const int f  = (u >> 5) & 3;
        const int i2 = u >> 7;                // 0..3
        if (i0 + i2 >= DOUT) continue;        // partial last i-group
        const float* Lb = &lds[i2][f][0][0];
        float4 rs[HROWS];
#pragma unroll
        for (int gg = 0; gg < HROWS; ++gg) {
            const float* Lr = Lb + gg * WW;
            float4 m  = *(const float4*)(Lr + uq * 4);
            float lft = (uq > 0)  ? Lr[uq * 4 - 1] : 0.f;
            float rgt = (uq < 31) ? Lr[uq * 4 + 4] : 0.f;
            rs[gg].x = lft + m.x + m.y;
            rs[gg].y = m.x + m.y + m.z;
            rs[gg].z = m.y + m.z + m.w;
            rs[gg].w = m.z + m.w + rgt;
        }
        float* op = out + ((b * FDIM + f) * DOUT + (i0 + i2)) * HW + h0 * WW + uq * 4;
#pragma unroll
        for (int r = 0; r < TROWS; ++r) {
            nfloat4 s;
            s.x = rs[r].x + rs[r + 1].x + rs[r + 2].x;
            s.y = rs[r].y + rs[r + 1].y + rs[r + 2].y;
            s.z = rs[r].z + rs[r + 1].z + rs[r + 2].z;
            s.w = rs[r].w + rs[r + 1].w + rs[r + 2].w;
            s.x = (s.x >= 0.f) ? s.x : 0.2f * s.x;
            s.y = (s.y >= 0.f) ? s.y : 0.2f * s.y;
            s.z = (s.z >= 0.f) ? s.z : 0.2f * s.z;
            s.w = (s.w >= 0.f) ? s.w : 0.2f * s.w;
            __builtin_nontemporal_store(s, (nfloat4*)(op + r * WW));
        }
    }
}

extern "C" void kernel_launch(void* const* d_in, const int* in_sizes, int n_in,
                              void* d_out, int out_size, void* d_ws, size_t ws_size,
                              hipStream_t stream) {
    const float* x    = (const float*)d_in[0];   // [4,4,16,128,128]
    const float* wgt  = (const float*)d_in[1];   // [4,1,4,3,128,128]
    const float* bias = (const float*)d_in[2];   // [4,1,4,3,128,128]
    float* out  = (float*)d_out;                 // [4,4,14,128,128]
    float* bsum = (float*)d_ws;                  // 65536 floats = 256 KB

    bsum_kernel<<<64, 256, 0, stream>>>((const float4*)bias, (float4*)bsum);
    linerconv_main<<<NB * NIG * NTILE, 384, 0, stream>>>(x, wgt, bsum, out);
}

// Round 8
// 24.381 us; speedup vs baseline: 4.0361x; 4.0361x over previous
//
#include <hip/hip_runtime.h>

// Problem constants (match reference)
#define HH    128
#define WW    128
#define CDIM  4
#define DK    3
#define FDIM  4
#define DEPTH 16
#define DOUT  14
#define NB    4
#define HW    (HH * WW)          // 16384
#define TROWS 4                  // output rows per block
#define HROWS (TROWS + 2)        // halo rows of Q per block
#define NTILE (HH / TROWS)       // 32 h-tiles
#define IB    4                  // i-values per block
#define NIG   4                  // i-groups: {0-3,4-7,8-11,12-13(partial)}
#define NPL   (IB + DK - 1)      // 6 x-planes per c

typedef float nfloat4 __attribute__((ext_vector_type(4)));  // native vec for nt-store

// ---------------------------------------------------------------------------
// Kernel A: bsum[f,h,w] = sum_{c,dd} bias[f,0,c,dd,h,w]   (float4-vectorized)
// ---------------------------------------------------------------------------
__global__ __launch_bounds__(256) void bsum_kernel(const float4* __restrict__ bias,
                                                   float4* __restrict__ bsum) {
    int idx = blockIdx.x * 256 + threadIdx.x;     // over f*H*W/4 = 16384
    int f   = idx >> 12;
    int hw4 = idx & 4095;
    const float4* bp = bias + f * (CDIM * DK * (HW / 4)) + hw4;
    float4 s = make_float4(0.f, 0.f, 0.f, 0.f);
#pragma unroll
    for (int c = 0; c < CDIM; ++c)
#pragma unroll
        for (int dd = 0; dd < DK; ++dd) {
            float4 v = bp[(c * DK + dd) * (HW / 4)];
            s.x += v.x; s.y += v.y; s.z += v.z; s.w += v.w;
        }
    bsum[idx] = s;
}

// ---------------------------------------------------------------------------
// Kernel B: fused Q + 3x3 box-sum + leaky ReLU, 4 depth-outputs per block.
// 384 threads = 6 waves; wave r = halo row r. Lanes 0-31 accumulate c=0,1;
// lanes 32-63 accumulate c=2,3; combined via __shfl_xor(.,32).
// ALL register-array indices are compile-time constants (scratch avoidance:
// the LDS-write fans out via a chalf branch with constant acc indices).
// ---------------------------------------------------------------------------
__global__ __launch_bounds__(384, 3) void linerconv_main(const float* __restrict__ x,
                                                         const float* __restrict__ wgt,
                                                         const float* __restrict__ bsum,
                                                         float* __restrict__ out) {
    const int blk  = blockIdx.x;
    const int tile = blk & (NTILE - 1);
    const int ig   = (blk >> 5) & (NIG - 1);
    const int b    = blk >> 7;
    const int i0   = ig * IB;                 // 0,4,8,12 (last group: 2 i only)
    const int h0   = tile * TROWS;

    __shared__ float lds[IB][FDIM][HROWS][WW]; // 4*4*6*128*4B = 48 KB

    const int tid   = threadIdx.x;
    const int row   = tid >> 6;               // wave id = halo row 0..5
    const int lane  = tid & 63;
    const int chalf = lane >> 5;              // 0: c=0,1   1: c=2,3
    const int q     = lane & 31;
    const int g     = h0 - 1 + row;

    // ---- Phase 1 ----
    if (g >= 0 && g < HH) {
        const int base_hw = g * WW + q * 4;
        const float* xb = x + (b * CDIM * DEPTH + i0) * HW + base_hw;
        const float* wb = wgt + base_hw;
        float4 acc[IB][FDIM];
        if (chalf == 0) {
#pragma unroll
            for (int f = 0; f < FDIM; ++f) {
                float4 bv = *(const float4*)(bsum + f * HW + base_hw);
#pragma unroll
                for (int i2 = 0; i2 < IB; ++i2) acc[i2][f] = bv;
            }
        } else {
            float4 z = make_float4(0.f, 0.f, 0.f, 0.f);
#pragma unroll
            for (int i2 = 0; i2 < IB; ++i2)
#pragma unroll
                for (int f = 0; f < FDIM; ++f) acc[i2][f] = z;
        }
#pragma unroll
        for (int c2 = 0; c2 < 2; ++c2) {
            const int cofs = (chalf * 2 + c2) * (DEPTH * HW);   // runtime addr ok
            float4 xp[NPL];                   // planes i0 .. i0+5 (guarded)
#pragma unroll
            for (int j = 0; j < NPL; ++j)
                xp[j] = (i0 + j < DEPTH)
                      ? *(const float4*)(xb + cofs + j * HW)
                      : make_float4(0.f, 0.f, 0.f, 0.f);
            const int wofs = (chalf * 2 + c2) * (DK * HW);
#pragma unroll
            for (int dd = 0; dd < DK; ++dd) {
#pragma unroll
                for (int f = 0; f < FDIM; ++f) {
                    float4 wv = *(const float4*)(wb + f * (CDIM * DK * HW) + wofs + dd * HW);
#pragma unroll
                    for (int i2 = 0; i2 < IB; ++i2) {
                        acc[i2][f].x += xp[i2 + dd].x * wv.x;
                        acc[i2][f].y += xp[i2 + dd].y * wv.y;
                        acc[i2][f].z += xp[i2 + dd].z * wv.z;
                        acc[i2][f].w += xp[i2 + dd].w * wv.w;
                    }
                }
            }
        }
        // combine the two c-halves across the 32-lane boundary (const indices)
#pragma unroll
        for (int i2 = 0; i2 < IB; ++i2)
#pragma unroll
            for (int f = 0; f < FDIM; ++f) {
                acc[i2][f].x += __shfl_xor(acc[i2][f].x, 32);
                acc[i2][f].y += __shfl_xor(acc[i2][f].y, 32);
                acc[i2][f].z += __shfl_xor(acc[i2][f].z, 32);
                acc[i2][f].w += __shfl_xor(acc[i2][f].w, 32);
            }
        // each half writes 2 i2-planes — register indices compile-time in both arms
        if (chalf == 0) {
#pragma unroll
            for (int f = 0; f < FDIM; ++f) {
                *(float4*)&lds[0][f][row][q * 4] = acc[0][f];
                *(float4*)&lds[1][f][row][q * 4] = acc[1][f];
            }
        } else {
#pragma unroll
            for (int f = 0; f < FDIM; ++f) {
                *(float4*)&lds[2][f][row][q * 4] = acc[2][f];
                *(float4*)&lds[3][f][row][q * 4] = acc[3][f];
            }
        }
    } else {
        float4 z = make_float4(0.f, 0.f, 0.f, 0.f);
        const int i2b = chalf * 2;            // LDS address may be runtime
#pragma unroll
        for (int k = 0; k < 2; ++k)
#pragma unroll
            for (int f = 0; f < FDIM; ++f)
                *(float4*)&lds[i2b + k][f][row][q * 4] = z;
    }
    __syncthreads();

    // ---- Phase 2: vectorized column box sums + leaky, float4 nt-stores ----
    // quad-columns: (i2, f, q) = 4*4*32 = 512 over 384 threads.
    for (int u = tid; u < IB * FDIM * 32; u += 384) {
        const int uq = u & 31;
        const int f  = (u >> 5) & 3;
        const int i2 = u >> 7;                // 0..3
        if (i0 + i2 >= DOUT) continue;        // partial last i-group
        const float* Lb = &lds[i2][f][0][0];  // runtime LDS base — fine
        float4 rs[HROWS];
#pragma unroll
        for (int gg = 0; gg < HROWS; ++gg) {
            const float* Lr = Lb + gg * WW;
            float4 m  = *(const float4*)(Lr + uq * 4);
            float lft = (uq > 0)  ? Lr[uq * 4 - 1] : 0.f;
            float rgt = (uq < 31) ? Lr[uq * 4 + 4] : 0.f;
            rs[gg].x = lft + m.x + m.y;
            rs[gg].y = m.x + m.y + m.z;
            rs[gg].z = m.y + m.z + m.w;
            rs[gg].w = m.z + m.w + rgt;
        }
        float* op = out + ((b * FDIM + f) * DOUT + (i0 + i2)) * HW + h0 * WW + uq * 4;
#pragma unroll
        for (int r = 0; r < TROWS; ++r) {
            nfloat4 s;
            s.x = rs[r].x + rs[r + 1].x + rs[r + 2].x;
            s.y = rs[r].y + rs[r + 1].y + rs[r + 2].y;
            s.z = rs[r].z + rs[r + 1].z + rs[r + 2].z;
            s.w = rs[r].w + rs[r + 1].w + rs[r + 2].w;
            s.x = (s.x >= 0.f) ? s.x : 0.2f * s.x;
            s.y = (s.y >= 0.f) ? s.y : 0.2f * s.y;
            s.z = (s.z >= 0.f) ? s.z : 0.2f * s.z;
            s.w = (s.w >= 0.f) ? s.w : 0.2f * s.w;
            __builtin_nontemporal_store(s, (nfloat4*)(op + r * WW));
        }
    }
}

extern "C" void kernel_launch(void* const* d_in, const int* in_sizes, int n_in,
                              void* d_out, int out_size, void* d_ws, size_t ws_size,
                              hipStream_t stream) {
    const float* x    = (const float*)d_in[0];   // [4,4,16,128,128]
    const float* wgt  = (const float*)d_in[1];   // [4,1,4,3,128,128]
    const float* bias = (const float*)d_in[2];   // [4,1,4,3,128,128]
    float* out  = (float*)d_out;                 // [4,4,14,128,128]
    float* bsum = (float*)d_ws;                  // 65536 floats = 256 KB

    bsum_kernel<<<64, 256, 0, stream>>>((const float4*)bias, (float4*)bsum);
    linerconv_main<<<NB * NIG * NTILE, 384, 0, stream>>>(x, wgt, bsum, out);
}

// Round 9
// 18.889 us; speedup vs baseline: 5.2097x; 1.2908x over previous
//
#include <hip/hip_runtime.h>

// Problem constants (match reference)
#define HH    128
#define WW    128
#define CDIM  4
#define DK    3
#define FDIM  4
#define DEPTH 16
#define DOUT  14
#define NB    4
#define HW    (HH * WW)          // 16384
#define TROWS 4                  // output rows per block
#define HROWS (TROWS + 2)        // halo rows of Q per block
#define NTILE (HH / TROWS)       // 32 h-tiles
#define NIG   4                  // i-groups: {0-3,4-7,8-11,12-13(partial)}

#define NW4   (FDIM * CDIM * DK * HW / 4)   // 196608 weight float4s
#define WCONV_BLOCKS 48                     // 48 * 256 * 16 = 196608

typedef float nfloat4 __attribute__((ext_vector_type(4)));  // native vec for nt-store

__device__ __forceinline__ float bf2f(unsigned short u) {
    return __uint_as_float(((unsigned int)u) << 16);
}
__device__ __forceinline__ unsigned short f2bf_rtne(float f) {
    unsigned int u = __float_as_uint(f);
    u += 0x7FFFu + ((u >> 16) & 1u);        // round-to-nearest-even
    return (unsigned short)(u >> 16);
}

// ---------------------------------------------------------------------------
// Kernel A (fused pre-pass):
//  blocks 0..63   : bsum[f,h,w] = sum_{c,dd} bias[f,0,c,dd,h,w]  (float4)
//  blocks 64..111 : weight f32 -> bf16 (RTN-even) repack
// ---------------------------------------------------------------------------
__global__ __launch_bounds__(256) void prepass_kernel(const float4* __restrict__ bias,
                                                      const float4* __restrict__ wgt,
                                                      float4* __restrict__ bsum,
                                                      ushort4* __restrict__ w16) {
    const int blk = blockIdx.x;
    const int tid = threadIdx.x;
    if (blk < 64) {
        int idx = blk * 256 + tid;                 // over f*H*W/4 = 16384
        int f   = idx >> 12;
        int hw4 = idx & 4095;
        const float4* bp = bias + f * (CDIM * DK * (HW / 4)) + hw4;
        float4 s = make_float4(0.f, 0.f, 0.f, 0.f);
#pragma unroll
        for (int c = 0; c < CDIM; ++c)
#pragma unroll
            for (int dd = 0; dd < DK; ++dd) {
                float4 v = bp[(c * DK + dd) * (HW / 4)];
                s.x += v.x; s.y += v.y; s.z += v.z; s.w += v.w;
            }
        bsum[idx] = s;
    } else {
        const int local = blk - 64;                // 0..47
#pragma unroll
        for (int k = 0; k < 16; ++k) {
            int idx = local * 4096 + k * 256 + tid;
            float4 v = wgt[idx];
            ushort4 o;
            o.x = f2bf_rtne(v.x); o.y = f2bf_rtne(v.y);
            o.z = f2bf_rtne(v.z); o.w = f2bf_rtne(v.w);
            w16[idx] = o;
        }
    }
}

// ---------------------------------------------------------------------------
// Kernel B: fused Q + 3x3 box-sum + leaky ReLU, 4 depth-outputs per block.
// R5 structure (best known: 18.5 us) with bf16 weights (half the dominant
// traffic). Block: (b, i-group, 4-row h-tile); 192 of 256 threads in phase 1.
// ---------------------------------------------------------------------------
__global__ __launch_bounds__(256, 2) void linerconv_main(const float* __restrict__ x,
                                                         const unsigned short* __restrict__ w16,
                                                         const float* __restrict__ bsum,
                                                         float* __restrict__ out) {
    const int blk  = blockIdx.x;
    const int tile = blk & (NTILE - 1);
    const int ig   = (blk >> 5) & (NIG - 1);
    const int b    = blk >> 7;
    const int i0   = ig * 4;                  // 0,4,8,12 (last group: 2 i only)
    const int h0   = tile * TROWS;
    const bool full = (ig != NIG - 1);

    __shared__ float lds[4][FDIM][HROWS][WW]; // 48 KB

    const int tid = threadIdx.x;

    // ---- Phase 1: 192 threads fill HROWS x WW of Q for nI i and 4 f ----
    if (tid < HROWS * 32) {
        const int row = tid >> 5;             // 0..5
        const int q   = tid & 31;
        const int g   = h0 - 1 + row;
        if (g >= 0 && g < HH) {
            const int base_hw = g * WW + q * 4;
            const float* xb = x + (b * CDIM * DEPTH + i0) * HW + base_hw;
            const unsigned short* wb = w16 + base_hw;
            if (full) {
                float4 acc[4][FDIM];
#pragma unroll
                for (int f = 0; f < FDIM; ++f) {
                    float4 bv = *(const float4*)(bsum + f * HW + base_hw);
#pragma unroll
                    for (int i2 = 0; i2 < 4; ++i2) acc[i2][f] = bv;
                }
#pragma unroll
                for (int c = 0; c < CDIM; ++c) {
                    float4 xp[6];                 // planes i0 .. i0+5
#pragma unroll
                    for (int j = 0; j < 6; ++j)
                        xp[j] = *(const float4*)(xb + c * (DEPTH * HW) + j * HW);
#pragma unroll
                    for (int dd = 0; dd < DK; ++dd) {
#pragma unroll
                        for (int f = 0; f < FDIM; ++f) {
                            ushort4 wu = *(const ushort4*)(wb + ((f * CDIM + c) * DK + dd) * HW);
                            float wx = bf2f(wu.x), wy = bf2f(wu.y);
                            float wz = bf2f(wu.z), ww = bf2f(wu.w);
#pragma unroll
                            for (int i2 = 0; i2 < 4; ++i2) {
                                acc[i2][f].x += xp[i2 + dd].x * wx;
                                acc[i2][f].y += xp[i2 + dd].y * wy;
                                acc[i2][f].z += xp[i2 + dd].z * wz;
                                acc[i2][f].w += xp[i2 + dd].w * ww;
                            }
                        }
                    }
                }
#pragma unroll
                for (int i2 = 0; i2 < 4; ++i2)
#pragma unroll
                    for (int f = 0; f < FDIM; ++f)
                        *(float4*)&lds[i2][f][row][q * 4] = acc[i2][f];
            } else {
                // partial group: i = 12,13 -> planes 12..15 only
                float4 acc[2][FDIM];
#pragma unroll
                for (int f = 0; f < FDIM; ++f) {
                    float4 bv = *(const float4*)(bsum + f * HW + base_hw);
                    acc[0][f] = bv;
                    acc[1][f] = bv;
                }
#pragma unroll
                for (int c = 0; c < CDIM; ++c) {
                    float4 xp[4];
#pragma unroll
                    for (int j = 0; j < 4; ++j)
                        xp[j] = *(const float4*)(xb + c * (DEPTH * HW) + j * HW);
#pragma unroll
                    for (int dd = 0; dd < DK; ++dd) {
#pragma unroll
                        for (int f = 0; f < FDIM; ++f) {
                            ushort4 wu = *(const ushort4*)(wb + ((f * CDIM + c) * DK + dd) * HW);
                            float wx = bf2f(wu.x), wy = bf2f(wu.y);
                            float wz = bf2f(wu.z), ww = bf2f(wu.w);
#pragma unroll
                            for (int i2 = 0; i2 < 2; ++i2) {
                                acc[i2][f].x += xp[i2 + dd].x * wx;
                                acc[i2][f].y += xp[i2 + dd].y * wy;
                                acc[i2][f].z += xp[i2 + dd].z * wz;
                                acc[i2][f].w += xp[i2 + dd].w * ww;
                            }
                        }
                    }
                }
#pragma unroll
                for (int i2 = 0; i2 < 2; ++i2)
#pragma unroll
                    for (int f = 0; f < FDIM; ++f)
                        *(float4*)&lds[i2][f][row][q * 4] = acc[i2][f];
            }
        } else {
            float4 z = make_float4(0.f, 0.f, 0.f, 0.f);
#pragma unroll
            for (int i2 = 0; i2 < 4; ++i2)
#pragma unroll
                for (int f = 0; f < FDIM; ++f)
                    *(float4*)&lds[i2][f][row][q * 4] = z;
        }
    }
    __syncthreads();

    // ---- Phase 2: vectorized column box sums + leaky, float4 nt-stores ----
    auto do_quadcol = [&](int idx) {
        const int q  = idx & 31;
        const int f  = (idx >> 5) & 3;
        const int i2 = idx >> 7;
        const float* Lb = &lds[i2][f][0][0];
        float4 rs[HROWS];
#pragma unroll
        for (int g = 0; g < HROWS; ++g) {
            const float* Lr = Lb + g * WW;
            float4 m  = *(const float4*)(Lr + q * 4);
            float lft = (q > 0)  ? Lr[q * 4 - 1] : 0.f;
            float rgt = (q < 31) ? Lr[q * 4 + 4] : 0.f;
            rs[g].x = lft + m.x + m.y;
            rs[g].y = m.x + m.y + m.z;
            rs[g].z = m.y + m.z + m.w;
            rs[g].w = m.z + m.w + rgt;
        }
        float* op = out + ((b * FDIM + f) * DOUT + (i0 + i2)) * HW + h0 * WW + q * 4;
#pragma unroll
        for (int r = 0; r < TROWS; ++r) {
            nfloat4 s;
            s.x = rs[r].x + rs[r + 1].x + rs[r + 2].x;
            s.y = rs[r].y + rs[r + 1].y + rs[r + 2].y;
            s.z = rs[r].z + rs[r + 1].z + rs[r + 2].z;
            s.w = rs[r].w + rs[r + 1].w + rs[r + 2].w;
            s.x = (s.x >= 0.f) ? s.x : 0.2f * s.x;
            s.y = (s.y >= 0.f) ? s.y : 0.2f * s.y;
            s.z = (s.z >= 0.f) ? s.z : 0.2f * s.z;
            s.w = (s.w >= 0.f) ? s.w : 0.2f * s.w;
            __builtin_nontemporal_store(s, (nfloat4*)(op + r * WW));
        }
    };
    do_quadcol(tid);
    if (full) do_quadcol(tid + 256);
}

extern "C" void kernel_launch(void* const* d_in, const int* in_sizes, int n_in,
                              void* d_out, int out_size, void* d_ws, size_t ws_size,
                              hipStream_t stream) {
    const float* x    = (const float*)d_in[0];   // [4,4,16,128,128]
    const float* wgt  = (const float*)d_in[1];   // [4,1,4,3,128,128]
    const float* bias = (const float*)d_in[2];   // [4,1,4,3,128,128]
    float* out  = (float*)d_out;                 // [4,4,14,128,128]

    float*          bsum = (float*)d_ws;                         // 256 KB
    unsigned short* w16  = (unsigned short*)((char*)d_ws + 65536 * 4);  // 1.5 MB

    prepass_kernel<<<64 + WCONV_BLOCKS, 256, 0, stream>>>(
        (const float4*)bias, (const float4*)wgt, (float4*)bsum, (ushort4*)w16);
    linerconv_main<<<NB * NIG * NTILE, 256, 0, stream>>>(x, w16, bsum, out);
}